// Round 15
// baseline (92.992 us; speedup 1.0000x reference)
//
#include <hip/hip_runtime.h>
#include <float.h>

#define BB 4
#define HH 8
#define BHN 32
#define NTOK 4096
#define DD 64
#define MM 64
#define PAD 68
#define GPART 16

typedef _Float16 f16;
typedef __attribute__((ext_vector_type(4))) _Float16 f16x4;
typedef __attribute__((ext_vector_type(8))) _Float16 f16x8;
typedef __attribute__((ext_vector_type(4))) float f32x4;

union V8U { f16x8 v; f16x4 q[2]; };

__device__ __forceinline__ void fsplit(float v, f16* h, f16* l) {
  f16 hh = (f16)v;
  *h = hh;
  *l = (f16)(v - (float)hh);
}

// plain f16 (2-chain)
__device__ __forceinline__ f32x4 mm2(f16x8 a0, f16x8 a1, f16x8 b0, f16x8 b1) {
  f32x4 c = {0.f, 0.f, 0.f, 0.f};
  c = __builtin_amdgcn_mfma_f32_16x16x32_f16(a0, b0, c, 0, 0, 0);
  c = __builtin_amdgcn_mfma_f32_16x16x32_f16(a1, b1, c, 0, 0, 0);
  return c;
}

// ---------------- 4x4-tile 64x64x64 matmul helper (fp32 scalar)
template<int LDA, int LDB>
__device__ __forceinline__ void mm_acc(float acc[4][4],
    const float (*A)[LDA], const float (*B)[LDB], int ti, int tj) {
  #pragma unroll
  for (int k4 = 0; k4 < 16; ++k4) {
    float a[4][4], b[4][4];
    #pragma unroll
    for (int x = 0; x < 4; ++x) {
      float4 t = *(const float4*)&A[ti*4+x][k4*4];
      a[x][0]=t.x; a[x][1]=t.y; a[x][2]=t.z; a[x][3]=t.w;
    }
    #pragma unroll
    for (int kk = 0; kk < 4; ++kk) {
      float4 t = *(const float4*)&B[k4*4+kk][tj*4];
      b[kk][0]=t.x; b[kk][1]=t.y; b[kk][2]=t.z; b[kk][3]=t.w;
    }
    #pragma unroll
    for (int kk = 0; kk < 4; ++kk)
      #pragma unroll
      for (int x = 0; x < 4; ++x)
        #pragma unroll
        for (int y = 0; y < 4; ++y)
          acc[x][y] = fmaf(a[x][kk], b[kk][y], acc[x][y]);
  }
}

// ---------------- row sums for selection; also zero-inits SYNC (block 0)
__global__ __launch_bounds__(256) void k_somme(const float* __restrict__ Kg,
    const float* __restrict__ Qg, const int* __restrict__ mask,
    float* __restrict__ somK, float* __restrict__ somQ,
    unsigned int* __restrict__ syncp) {
  int tid = threadIdx.x;
  if (blockIdx.x == 0 && tid == 0) {
    #pragma unroll
    for (int i = 0; i < 34; ++i) syncp[i] = 0u;    // SCAL, W3CNT[32]
  }
  int lane = tid & 63;
  long grow = (long)blockIdx.x * 16 + (tid >> 6) * 4 + (lane >> 4);
  int which = grow >= (long)(BHN * NTOK);
  long row = which ? grow - (long)BHN * NTOK : grow;   // bh*N + n
  int n = (int)(row & (NTOK - 1));
  int bh = (int)(row >> 12);
  int b = bh >> 3;
  const float* src = which ? Qg : Kg;
  float4 v = *((const float4*)(src + row * DD) + (lane & 15));
  float s = v.x + v.y + v.z + v.w;
  s += __shfl_xor(s, 1); s += __shfl_xor(s, 2);
  s += __shfl_xor(s, 4); s += __shfl_xor(s, 8);
  if ((lane & 15) == 0) {
    float out = (n == 0 || mask[b * NTOK + n] != 0) ? -FLT_MAX : s;
    (which ? somQ : somK)[row] = out;
  }
}

// ---------------- per-bh: BOTH radix top-63 selects (512 thr, two 256-halves)
// then u = row-softmax(nr@nc^T) -> global, colsum-max -> atomicMax(SCAL).
__global__ __launch_bounds__(512) void k_select(const float* __restrict__ Kg,
    const float* __restrict__ Qg, const float* __restrict__ somK,
    const float* __restrict__ somQ, float* __restrict__ nc, float* __restrict__ nr,
    float* __restrict__ ug, unsigned int* __restrict__ scal) {
  __shared__ __align__(16) char sm[40960];   // select: keys 2x16KB + wb 2x4KB; u: A+BT+cs
  __shared__ int wsum[2][4], wsumB[2][4], sh_bin[2], sh_need[2];
  __shared__ int sel[2][MM];
  int bh = blockIdx.x;
  int tid = threadIdx.x;
  int half = tid >> 8, t = tid & 255;
  int lane = tid & 63, wv = (tid >> 6) & 3;
  unsigned int* keys = (unsigned int*)sm + half * 4096;
  unsigned int* wbp  = (unsigned int*)(sm + 32768) + half * 1024;   // [4][256]

  const float* som = (half ? somQ : somK) + (long)bh * NTOK;
  for (int i = t; i < NTOK; i += 256) {
    float f = som[i];
    unsigned int u = __float_as_uint(f);
    u = (u & 0x80000000u) ? ~u : (u | 0x80000000u);   // monotone map, ascending
    keys[i] = (i == 0) ? 0u : u;                      // token 0 out of competition
  }
  unsigned int pref = 0; int need = MM - 1;           // 63
  for (int pass = 0; pass < 4; ++pass) {
    int shift = 24 - pass * 8;
    unsigned int pm = (pass == 0) ? 0u : (0xFFFFFFFFu << (32 - 8 * pass));
    wbp[t] = 0; wbp[t + 256] = 0; wbp[t + 512] = 0; wbp[t + 768] = 0;
    __syncthreads();
    for (int i = t; i < NTOK; i += 256) {
      unsigned int k = keys[i];
      if ((k & pm) == pref) atomicAdd(&wbp[wv * 256 + ((k >> shift) & 255)], 1u);
    }
    __syncthreads();
    int binr = 255 - t;                               // reversed -> suffix sum
    int cnt = (int)(wbp[binr] + wbp[256 + binr] + wbp[512 + binr] + wbp[768 + binr]);
    int v = cnt;
    #pragma unroll
    for (int d = 1; d < 64; d <<= 1) {
      int tt = __shfl_up(v, d);
      if (lane >= d) v += tt;
    }
    if (lane == 63) wsum[half][wv] = v;
    __syncthreads();
    int off = 0;
    #pragma unroll
    for (int w = 0; w < 4; ++w) off += (w < wv) ? wsum[half][w] : 0;
    v += off;
    int above = v - cnt;
    if (v >= need && above < need) { sh_bin[half] = binr; sh_need[half] = need - above; }
    __syncthreads();
    pref |= ((unsigned int)sh_bin[half]) << shift;
    need = sh_need[half];
  }
  unsigned int thr = pref;

  int base = t * 16;
  int ctie = 0;
  #pragma unroll
  for (int j = 0; j < 16; ++j) ctie += (keys[base + j] == thr);
  int v2 = ctie;
  #pragma unroll
  for (int d = 1; d < 64; d <<= 1) {
    int tt = __shfl_up(v2, d);
    if (lane >= d) v2 += tt;
  }
  if (lane == 63) wsum[half][wv] = v2;
  __syncthreads();
  int offt = 0;
  #pragma unroll
  for (int w = 0; w < 4; ++w) offt += (w < wv) ? wsum[half][w] : 0;
  int tie_excl = v2 + offt - ctie;

  int tieoff = tie_excl, cnt2 = 0;
  #pragma unroll
  for (int j = 0; j < 16; ++j) {
    unsigned int k = keys[base + j];
    int f = (k > thr) ? 1 : 0;
    if (k == thr) { f = (tieoff < need) ? 1 : 0; ++tieoff; }
    if (base + j == 0) f = 1;
    cnt2 += f;
  }
  int v3 = cnt2;
  #pragma unroll
  for (int d = 1; d < 64; d <<= 1) {
    int tt = __shfl_up(v3, d);
    if (lane >= d) v3 += tt;
  }
  if (lane == 63) wsumB[half][wv] = v3;
  __syncthreads();
  int offc = 0;
  #pragma unroll
  for (int w = 0; w < 4; ++w) offc += (w < wv) ? wsumB[half][w] : 0;
  int o = v3 + offc - cnt2;
  tieoff = tie_excl;
  #pragma unroll
  for (int j = 0; j < 16; ++j) {
    unsigned int k = keys[base + j];
    int f = (k > thr) ? 1 : 0;
    if (k == thr) { f = (tieoff < need) ? 1 : 0; ++tieoff; }
    if (base + j == 0) f = 1;
    if (f) sel[half][o++] = base + j;
  }
  __syncthreads();                                    // sel ready; keys/wb dead

  // ---- gather to global + stage into LDS overlay (A = nr rows, BT = nc^T) ----
  float (*A)[PAD] = (float(*)[PAD])sm;                // 17408
  float (*BT)[MM] = (float(*)[MM])(sm + 17408);       // 16384
  float (*cs)[MM] = (float(*)[MM])(sm + 33792);       // 1024
  const float* src = half ? Qg : Kg;
  float* dst = (half ? nr : nc) + (long)bh * MM * DD;
  float scale = half ? 0.125f : 1.0f;
  for (int e = t; e < 1024; e += 256) {
    int i = e >> 4, d4 = e & 15;
    float4 v = *(const float4*)&src[((long)bh * NTOK + sel[half][i]) * DD + d4 * 4];
    v.x *= scale; v.y *= scale; v.z *= scale; v.w *= scale;
    *(float4*)&dst[i * DD + d4 * 4] = v;
    if (half) {
      *(float4*)&A[i][d4*4] = v;
    } else {
      BT[d4*4+0][i] = v.x; BT[d4*4+1][i] = v.y;
      BT[d4*4+2][i] = v.z; BT[d4*4+3][i] = v.w;
    }
  }
  __syncthreads();

  // ---- u-phase: u = row-softmax(A @ BT) -> ug; colsum-max -> SCAL ----
  if (tid < 256) {
    int ti = tid >> 4, tj = tid & 15;
    float acc[4][4] = {};
    mm_acc<PAD, MM>(acc, A, BT, ti, tj);
    float e_[4][4];
    #pragma unroll
    for (int x = 0; x < 4; ++x)
      #pragma unroll
      for (int y = 0; y < 4; ++y) e_[x][y] = expf(acc[x][y]);
    float rsx[4];
    #pragma unroll
    for (int x = 0; x < 4; ++x) {
      rsx[x] = e_[x][0] + e_[x][1] + e_[x][2] + e_[x][3];
      rsx[x] += __shfl_xor(rsx[x], 1); rsx[x] += __shfl_xor(rsx[x], 2);
      rsx[x] += __shfl_xor(rsx[x], 4); rsx[x] += __shfl_xor(rsx[x], 8);
    }
    float cp[4] = {0.f, 0.f, 0.f, 0.f};
    #pragma unroll
    for (int x = 0; x < 4; ++x) {
      float inv = 1.f / rsx[x];
      float v0 = e_[x][0]*inv, v1 = e_[x][1]*inv, v2 = e_[x][2]*inv, v3 = e_[x][3]*inv;
      cp[0] += v0; cp[1] += v1; cp[2] += v2; cp[3] += v3;
      float4 ov; ov.x = v0; ov.y = v1; ov.z = v2; ov.w = v3;
      *(float4*)&ug[(long)bh*MM*MM + (ti*4+x)*MM + tj*4] = ov;
    }
    #pragma unroll
    for (int y = 0; y < 4; ++y) {
      cp[y] += __shfl_xor(cp[y], 16);
      cp[y] += __shfl_xor(cp[y], 32);
    }
    if (((tid >> 4) & 3) == 0) {
      #pragma unroll
      for (int y = 0; y < 4; ++y) cs[tid >> 6][tj*4 + y] = cp[y];
    }
  }
  __syncthreads();
  if (tid < 64) {
    float tot = cs[0][tid] + cs[1][tid] + cs[2][tid] + cs[3][tid];
    for (int off = 32; off; off >>= 1) tot = fmaxf(tot, __shfl_xor(tot, off));
    if (tid == 0) atomicMax(scal, __float_as_uint(tot));   // colsums > 0
  }
}

// =============== fused: Newton (u from global, c0 from SCAL) + Z (w3cnt spin) ===========
__device__ void newton_fused(char* smem, const float* __restrict__ ug,
    const unsigned int* __restrict__ scal, const float* __restrict__ nump,
    const float* __restrict__ denp, unsigned int* __restrict__ w3cnt,
    float* __restrict__ Zg, int bh) {
  f16 (*VT_h)[72] = (f16(*)[72])(smem);
  f16 (*Vr_h)[72] = (f16(*)[72])(smem + 9216);
  f16 (*PT_h)[72] = (f16(*)[72])(smem + 18432);
  f16 (*PT_l)[72] = (f16(*)[72])(smem + 27648);
  f16 (*RT_h)[72] = (f16(*)[72])(smem + 36864);
  f16 (*RT_l)[72] = (f16(*)[72])(smem + 46080);
  float (*Vi)[PAD] = (float(*)[PAD])(smem + 36864);   // last-iter output (over RT)
  int tid = threadIdx.x;
  int wave = tid >> 6, lane = tid & 63;
  int wr = wave >> 1, wc = wave & 1;
  int lm = lane & 15, hi = lane >> 4;

  float c0 = 1.0f / __uint_as_float(scal[0]);        // finalized by k_select
  const float* pu = ug + (long)bh * MM * MM;
  for (int e = tid; e < 4096; e += 512) {
    int i = e >> 6, j = e & 63;
    f16 h = (f16)(pu[e] * c0);
    VT_h[i][j] = h;                    // V0^T = c*K
    Vr_h[j][i] = h;                    // V0 = c*K^T
  }
  // K B-frag from global (u is L2-hot), SPLIT (needed in last iter's step 1)
  f16x8 kb_h[2], kb_l[2];
  {
    const float* p = pu + (wr*16 + lm) * 64;
    float kv[16];
    *(float4*)&kv[0]  = *(const float4*)(p + hi*8);
    *(float4*)&kv[4]  = *(const float4*)(p + hi*8 + 4);
    *(float4*)&kv[8]  = *(const float4*)(p + 32 + hi*8);
    *(float4*)&kv[12] = *(const float4*)(p + 36 + hi*8);
    #pragma unroll
    for (int j = 0; j < 8; ++j) {
      f16 h, l;
      fsplit(kv[j], &h, &l);     kb_h[0][j] = h; kb_l[0][j] = l;
      fsplit(kv[8+j], &h, &l);   kb_h[1][j] = h; kb_l[1][j] = l;
    }
  }
  __syncthreads();

  for (int it = 0; it < 6; ++it) {
    const bool last = (it == 5);

    // step 1: S^T slice = mfma(VT rows, K rows); split-K only when last
    f32x4 st[4];
    #pragma unroll
    for (int g = 0; g < 4; ++g) {
      f16x8 a0 = *(const f16x8*)&VT_h[g*16 + lm][hi*8];
      f16x8 a1 = *(const f16x8*)&VT_h[g*16 + lm][32 + hi*8];
      f32x4 c = mm2(a0, a1, kb_h[0], kb_h[1]);
      if (last) {
        c = __builtin_amdgcn_mfma_f32_16x16x32_f16(a0, kb_l[0], c, 0, 0, 0);
        c = __builtin_amdgcn_mfma_f32_16x16x32_f16(a1, kb_l[1], c, 0, 0, 0);
      }
      st[g] = c;
    }
    f16x8 sa[2];
    #pragma unroll
    for (int g = 0; g < 4; ++g)
      #pragma unroll
      for (int r = 0; r < 4; ++r)
        sa[g >> 1][(g & 1)*4 + r] = (f16)st[g][r];
    #pragma unroll
    for (int g = 0; g < 4; ++g) {
      if ((g >> 1) == wc) {
        #pragma unroll
        for (int r = 0; r < 4; ++r) {
          int i = g*16 + hi*4 + r, j = wr*16 + lm;
          float pv = (i == j ? 7.f : 0.f) - st[g][r];
          if (last) {
            f16 h, l; fsplit(pv, &h, &l);
            PT_h[i][j] = h; PT_l[i][j] = l;
          } else {
            PT_h[i][j] = (f16)pv;
          }
        }
      }
    }
    __syncthreads();

    // step 2: R = 15I - S@P -> RT
    #pragma unroll
    for (int cc2 = 0; cc2 < 2; ++cc2) {
      int cc = wc*2 + cc2;
      V8U bh0, bh1;
      bh0.q[0] = *(const f16x4*)&PT_h[cc*16 + lm][hi*4];
      bh0.q[1] = *(const f16x4*)&PT_h[cc*16 + lm][16 + hi*4];
      bh1.q[0] = *(const f16x4*)&PT_h[cc*16 + lm][32 + hi*4];
      bh1.q[1] = *(const f16x4*)&PT_h[cc*16 + lm][48 + hi*4];
      f32x4 a = mm2(sa[0], sa[1], bh0.v, bh1.v);
      if (last) {
        V8U bl0, bl1;
        bl0.q[0] = *(const f16x4*)&PT_l[cc*16 + lm][hi*4];
        bl0.q[1] = *(const f16x4*)&PT_l[cc*16 + lm][16 + hi*4];
        bl1.q[0] = *(const f16x4*)&PT_l[cc*16 + lm][32 + hi*4];
        bl1.q[1] = *(const f16x4*)&PT_l[cc*16 + lm][48 + hi*4];
        a = __builtin_amdgcn_mfma_f32_16x16x32_f16(sa[0], bl0.v, a, 0, 0, 0);
        a = __builtin_amdgcn_mfma_f32_16x16x32_f16(sa[1], bl1.v, a, 0, 0, 0);
      }
      f16x4 wh, wl;
      #pragma unroll
      for (int r = 0; r < 4; ++r) {
        int row = wr*16 + hi*4 + r, col = cc*16 + lm;
        float rv = (row == col ? 15.f : 0.f) - a[r];
        if (last) { f16 h, l; fsplit(rv, &h, &l); wh[r] = h; wl[r] = l; }
        else wh[r] = (f16)rv;
      }
      *(f16x4*)&RT_h[cc*16 + lm][wr*16 + hi*4] = wh;
      if (last) *(f16x4*)&RT_l[cc*16 + lm][wr*16 + hi*4] = wl;
    }
    __syncthreads();

    // step 3: W = 13I - S@R -> WT (into PT bufs)
    #pragma unroll
    for (int cc2 = 0; cc2 < 2; ++cc2) {
      int cc = wc*2 + cc2;
      V8U bh0, bh1;
      bh0.q[0] = *(const f16x4*)&RT_h[cc*16 + lm][hi*4];
      bh0.q[1] = *(const f16x4*)&RT_h[cc*16 + lm][16 + hi*4];
      bh1.q[0] = *(const f16x4*)&RT_h[cc*16 + lm][32 + hi*4];
      bh1.q[1] = *(const f16x4*)&RT_h[cc*16 + lm][48 + hi*4];
      f32x4 a = mm2(sa[0], sa[1], bh0.v, bh1.v);
      if (last) {
        V8U bl0, bl1;
        bl0.q[0] = *(const f16x4*)&RT_l[cc*16 + lm][hi*4];
        bl0.q[1] = *(const f16x4*)&RT_l[cc*16 + lm][16 + hi*4];
        bl1.q[0] = *(const f16x4*)&RT_l[cc*16 + lm][32 + hi*4];
        bl1.q[1] = *(const f16x4*)&RT_l[cc*16 + lm][48 + hi*4];
        a = __builtin_amdgcn_mfma_f32_16x16x32_f16(sa[0], bl0.v, a, 0, 0, 0);
        a = __builtin_amdgcn_mfma_f32_16x16x32_f16(sa[1], bl1.v, a, 0, 0, 0);
      }
      f16x4 wh, wl;
      #pragma unroll
      for (int r = 0; r < 4; ++r) {
        int row = wr*16 + hi*4 + r, col = cc*16 + lm;
        float wv = (row == col ? 13.f : 0.f) - a[r];
        if (last) { f16 h, l; fsplit(wv, &h, &l); wh[r] = h; wl[r] = l; }
        else wh[r] = (f16)wv;
      }
      *(f16x4*)&PT_h[cc*16 + lm][wr*16 + hi*4] = wh;
      if (last) *(f16x4*)&PT_l[cc*16 + lm][wr*16 + hi*4] = wl;
    }
    __syncthreads();

    // step 4: V' = 0.25 V@W
    f16x8 vh0 = *(const f16x8*)&Vr_h[wr*16 + lm][hi*8];
    f16x8 vh1 = *(const f16x8*)&Vr_h[wr*16 + lm][32 + hi*8];
    #pragma unroll
    for (int cc2 = 0; cc2 < 2; ++cc2) {
      int cc = wc*2 + cc2;
      f16x8 wh0 = *(const f16x8*)&PT_h[cc*16 + lm][hi*8];
      f16x8 wh1 = *(const f16x8*)&PT_h[cc*16 + lm][32 + hi*8];
      f32x4 a = mm2(vh0, vh1, wh0, wh1);
      if (last) {
        f16x8 wl0 = *(const f16x8*)&PT_l[cc*16 + lm][hi*8];
        f16x8 wl1 = *(const f16x8*)&PT_l[cc*16 + lm][32 + hi*8];
        a = __builtin_amdgcn_mfma_f32_16x16x32_f16(vh0, wl0, a, 0, 0, 0);
        a = __builtin_amdgcn_mfma_f32_16x16x32_f16(vh1, wl1, a, 0, 0, 0);
        #pragma unroll
        for (int r = 0; r < 4; ++r)
          Vi[wr*16 + hi*4 + r][cc*16 + lm] = 0.25f * a[r];
      } else {
        f16x4 th;
        #pragma unroll
        for (int r = 0; r < 4; ++r) {
          f16 h = (f16)(0.25f * a[r]);
          Vr_h[wr*16 + hi*4 + r][cc*16 + lm] = h;
          th[r] = h;
        }
        *(f16x4*)&VT_h[cc*16 + lm][wr*16 + hi*4] = th;
      }
    }
    __syncthreads();
  }

  // ---- Z phase: wait for this bh's w3 partials, then Z = Vinv @ (sum num / sum den) ----
  if (tid == 0) {
    while (__hip_atomic_load(&w3cnt[bh], __ATOMIC_ACQUIRE, __HIP_MEMORY_SCOPE_AGENT) < 8u)
      __builtin_amdgcn_s_sleep(1);
  }
  __syncthreads();
  float (*W)[PAD] = (float(*)[PAD])smem;            // over VT/Vr (free)
  float* dn = (float*)(smem + 54272);
  if (tid < 64) {
    float s = 0.f;
    #pragma unroll
    for (int g = 0; g < GPART; ++g) s += denp[((long)bh * GPART + g) * MM + tid];
    dn[tid] = s;
  }
  __syncthreads();
  for (int e = tid; e < 1024; e += 512) {
    int m = e >> 4, d4 = e & 15;
    float4 s = {0.f, 0.f, 0.f, 0.f};
    #pragma unroll
    for (int g = 0; g < GPART; ++g) {
      float4 t = *(const float4*)&nump[((long)bh * GPART + g) * (MM*DD) + m*DD + d4*4];
      s.x += t.x; s.y += t.y; s.z += t.z; s.w += t.w;
    }
    float inv = 1.f / dn[m];
    s.x *= inv; s.y *= inv; s.z *= inv; s.w *= inv;
    *(float4*)&W[m][d4*4] = s;
  }
  __syncthreads();
  if (tid < 256) {
    int ti = tid >> 4, tj = tid & 15;
    float acc[4][4] = {};
    mm_acc<PAD, PAD>(acc, Vi, W, ti, tj);
    #pragma unroll
    for (int x = 0; x < 4; ++x) {
      float4 o; o.x = acc[x][0]; o.y = acc[x][1]; o.z = acc[x][2]; o.w = acc[x][3];
      *(float4*)&Zg[(long)bh*MM*DD + (ti*4+x)*DD + tj*4] = o;
    }
  }
}

// w3 as two independent 256-thread halves in a 512-thread block; releases w3cnt[bh]
__device__ void w3_dev(char* smem, const float* __restrict__ Kg,
    const float* __restrict__ Vg, const int* __restrict__ maskg,
    const float* __restrict__ nr, float* __restrict__ nump,
    float* __restrict__ denp, unsigned int* __restrict__ w3cnt, int idx) {
  int bh = idx >> 3, grp = idx & 7, b = bh >> 3;
  int tid = threadIdx.x;
  int half = tid >> 8, t = tid & 255;
  f16 (*Ks)[72] = (f16(*)[72])(smem + half * 18432);
  f16 (*Vs)[72] = (f16(*)[72])(smem + half * 18432 + 9216);
  float* kmul = (float*)(smem + 36864) + half * 64;
  int lane = tid & 63;
  int lm = lane & 15, hi = lane >> 4;
  int wv = t >> 6;
  int m0 = wv * 16;
  int gslot = grp * 2 + half;

  f16x8 nrf[2];
  {
    const float* p = nr + (long)bh*MM*DD + (long)(m0 + lm)*DD + hi*8;
    float4 q0 = *(const float4*)p;
    float4 q1 = *(const float4*)(p + 4);
    float4 q2 = *(const float4*)(p + 32);
    float4 q3 = *(const float4*)(p + 36);
    nrf[0][0]=(f16)q0.x; nrf[0][1]=(f16)q0.y; nrf[0][2]=(f16)q0.z; nrf[0][3]=(f16)q0.w;
    nrf[0][4]=(f16)q1.x; nrf[0][5]=(f16)q1.y; nrf[0][6]=(f16)q1.z; nrf[0][7]=(f16)q1.w;
    nrf[1][0]=(f16)q2.x; nrf[1][1]=(f16)q2.y; nrf[1][2]=(f16)q2.z; nrf[1][3]=(f16)q2.w;
    nrf[1][4]=(f16)q3.x; nrf[1][5]=(f16)q3.y; nrf[1][6]=(f16)q3.z; nrf[1][7]=(f16)q3.w;
  }

  f32x4 nacc[4];
  #pragma unroll
  for (int dt = 0; dt < 4; ++dt) nacc[dt] = (f32x4){0.f, 0.f, 0.f, 0.f};
  float dsum = 0.f;

  for (int sc = 0; sc < 4; ++sc) {
    int n0c = (gslot * 4 + sc) * 64;
    if (sc) __syncthreads();
    for (int s = t; s < 1024; s += 256) {
      int row = s >> 4, c4 = s & 15;
      float4 kv = *(const float4*)&Kg[((long)bh*NTOK + n0c + row)*DD + c4*4];
      float4 vv = *(const float4*)&Vg[((long)bh*NTOK + n0c + row)*DD + c4*4];
      f16x4 kk = {(f16)kv.x, (f16)kv.y, (f16)kv.z, (f16)kv.w};
      f16x4 vv4 = {(f16)vv.x, (f16)vv.y, (f16)vv.z, (f16)vv.w};
      *(f16x4*)&Ks[row][c4*4] = kk;
      *(f16x4*)&Vs[row][c4*4] = vv4;
    }
    if (t < 64) kmul[t] = maskg[b * NTOK + n0c + t] ? 1.f : 0.f;
    __syncthreads();

    f32x4 stv[4];
    #pragma unroll
    for (int g = 0; g < 4; ++g) {
      f16x8 a0 = *(const f16x8*)&Ks[g*16 + lm][hi*8];
      f16x8 a1 = *(const f16x8*)&Ks[g*16 + lm][32 + hi*8];
      stv[g] = mm2(a0, a1, nrf[0], nrf[1]);
    }
    f16x8 pa[2];
    #pragma unroll
    for (int g = 0; g < 4; ++g) {
      #pragma unroll
      for (int r = 0; r < 4; ++r) {
        float p = __expf(stv[g][r]) * kmul[g*16 + hi*4 + r];
        dsum += p;
        pa[g >> 1][(g & 1)*4 + r] = (f16)p;
      }
    }
    #pragma unroll
    for (int dt = 0; dt < 4; ++dt) {
      f16x8 vb0, vb1;
      #pragma unroll
      for (int j = 0; j < 8; ++j) {
        int nrow = hi*4 + (j & 3) + 16*(j >> 2);
        vb0[j] = Vs[nrow][dt*16 + lm];
        vb1[j] = Vs[32 + nrow][dt*16 + lm];
      }
      nacc[dt] = __builtin_amdgcn_mfma_f32_16x16x32_f16(pa[0], vb0, nacc[dt], 0, 0, 0);
      nacc[dt] = __builtin_amdgcn_mfma_f32_16x16x32_f16(pa[1], vb1, nacc[dt], 0, 0, 0);
    }
  }
  float* pnum = nump + ((long)bh * GPART + gslot) * (MM * DD);
  #pragma unroll
  for (int dt = 0; dt < 4; ++dt)
    #pragma unroll
    for (int r = 0; r < 4; ++r)
      pnum[(m0 + hi*4 + r)*DD + dt*16 + lm] = nacc[dt][r];
  float d2 = dsum + __shfl_xor(dsum, 16);
  d2 += __shfl_xor(d2, 32);
  if (lane < 16)
    denp[((long)bh * GPART + gslot) * MM + m0 + lane] = d2;
  __syncthreads();     // all global stores drained (vmcnt(0) before barrier)
  if (tid == 0)
    __hip_atomic_fetch_add(&w3cnt[bh], 1u, __ATOMIC_RELEASE, __HIP_MEMORY_SCOPE_AGENT);
}

// merged launch: blocks [0,32) newton+z, blocks [32,288) w3. All 288 co-resident
// (LDS 55.3KB -> 2 blocks/CU) so the w3cnt spin is safe (newton <- w3 <- nothing).
__global__ __launch_bounds__(512, 4) void k_fuse(
    const float* __restrict__ ug, const unsigned int* __restrict__ scal,
    const float* __restrict__ Kg, const float* __restrict__ Vg,
    const int* __restrict__ maskg, const float* __restrict__ nr,
    float* __restrict__ nump, float* __restrict__ denp,
    unsigned int* __restrict__ w3cnt, float* __restrict__ Zg) {
  __shared__ __align__(16) char smem[55296];
  if (blockIdx.x < 32)
    newton_fused(smem, ug, scal, nump, denp, w3cnt, Zg, blockIdx.x);
  else
    w3_dev(smem, Kg, Vg, maskg, nr, nump, denp, w3cnt, blockIdx.x - 32);
}

// ---------------- MFMA X = row-softmax(Qs @ nc^T) @ Z  (swapped S^T trick)
__global__ __launch_bounds__(256) void k_final(const float* __restrict__ Qg,
    const float* __restrict__ nc, const float* __restrict__ Zg, float* __restrict__ Xg) {
  int bh = blockIdx.x, chunk = blockIdx.y;
  int tid = threadIdx.x;
  int wave = tid >> 6, lane = tid & 63;
  int lm = lane & 15, hi = lane >> 4;
  int n0 = chunk * 64;
  __shared__ f16 Qs[64][72];
  __shared__ f16 Ncs[64][72];
  __shared__ f16 Zs[64][72];
  for (int s = tid; s < 1024; s += 256) {
    int row = s >> 4, c4 = s & 15;
    float4 q = *(const float4*)&Qg[((long)bh*NTOK + n0 + row)*DD + c4*4];
    f16x4 qq = {(f16)(q.x*0.125f), (f16)(q.y*0.125f), (f16)(q.z*0.125f), (f16)(q.w*0.125f)};
    *(f16x4*)&Qs[row][c4*4] = qq;
    float4 cv = *(const float4*)&nc[(long)bh*MM*DD + row*DD + c4*4];
    f16x4 cc = {(f16)cv.x, (f16)cv.y, (f16)cv.z, (f16)cv.w};
    *(f16x4*)&Ncs[row][c4*4] = cc;
    float4 zv = *(const float4*)&Zg[(long)bh*MM*DD + row*DD + c4*4];
    f16x4 zz = {(f16)zv.x, (f16)zv.y, (f16)zv.z, (f16)zv.w};
    *(f16x4*)&Zs[row][c4*4] = zz;
  }
  __syncthreads();

  f16x8 qb0 = *(const f16x8*)&Qs[wave*16 + lm][hi*8];
  f16x8 qb1 = *(const f16x8*)&Qs[wave*16 + lm][32 + hi*8];
  f32x4 stv[4];
  #pragma unroll
  for (int mt = 0; mt < 4; ++mt) {
    f16x8 a0 = *(const f16x8*)&Ncs[mt*16 + lm][hi*8];
    f16x8 a1 = *(const f16x8*)&Ncs[mt*16 + lm][32 + hi*8];
    stv[mt] = mm2(a0, a1, qb0, qb1);
  }
  f16x8 pa[2];
  float dsum = 0.f;
  #pragma unroll
  for (int mt = 0; mt < 4; ++mt) {
    #pragma unroll
    for (int r = 0; r < 4; ++r) {
      float p = __expf(stv[mt][r]);
      dsum += p;
      pa[mt >> 1][(mt & 1)*4 + r] = (f16)p;
    }
  }
  float dtot = dsum + __shfl_xor(dsum, 16);
  dtot += __shfl_xor(dtot, 32);
  f32x4 xacc[4];
  #pragma unroll
  for (int dt = 0; dt < 4; ++dt) {
    f16x8 zb0, zb1;
    #pragma unroll
    for (int j = 0; j < 8; ++j) {
      int mrow = hi*4 + (j & 3) + 16*(j >> 2);
      zb0[j] = Zs[mrow][dt*16 + lm];
      zb1[j] = Zs[32 + mrow][dt*16 + lm];
    }
    f32x4 c = {0.f, 0.f, 0.f, 0.f};
    c = __builtin_amdgcn_mfma_f32_16x16x32_f16(pa[0], zb0, c, 0, 0, 0);
    c = __builtin_amdgcn_mfma_f32_16x16x32_f16(pa[1], zb1, c, 0, 0, 0);
    xacc[dt] = c;
  }
  float rn[4];
  #pragma unroll
  for (int r = 0; r < 4; ++r) rn[r] = 1.f / __shfl(dtot, hi*4 + r);
  #pragma unroll
  for (int dt = 0; dt < 4; ++dt)
    #pragma unroll
    for (int r = 0; r < 4; ++r)
      Xg[((long)bh*NTOK + n0 + wave*16 + hi*4 + r)*DD + dt*16 + lm] = xacc[dt][r] * rn[r];
}

extern "C" void kernel_launch(void* const* d_in, const int* in_sizes, int n_in,
                              void* d_out, int out_size, void* d_ws, size_t ws_size,
                              hipStream_t stream) {
  (void)in_sizes; (void)n_in; (void)out_size; (void)ws_size;
  const float* Qp = (const float*)d_in[0];
  const float* Kp = (const float*)d_in[1];
  const float* Vp = (const float*)d_in[2];
  const int* maskp = (const int*)d_in[3];
  float* out = (float*)d_out;

  float* wsf = (float*)d_ws;
  float* NUMP = wsf;                                // 32*16*4096
  float* DENP = NUMP + (long)BHN * GPART * MM * DD; // 32*16*64
  unsigned int* SYNC = (unsigned int*)(DENP + BHN * GPART * MM); // [0]=SCAL [1..33)=W3CNT
  float* UG = (float*)(SYNC + 64);                  // 32*4096
  float* NC = UG + BHN * MM * MM;
  float* NR = NC + BHN * MM * DD;
  float* Zb = NR + BHN * MM * DD;
  float* SK = Zb + BHN * MM * DD;
  float* SQ = SK + BHN * NTOK;

  unsigned int* SCAL = SYNC;
  unsigned int* W3CNT = SYNC + 1;

  k_somme<<<16384, 256, 0, stream>>>(Kp, Qp, maskp, SK, SQ, SYNC);
  k_select<<<32, 512, 0, stream>>>(Kp, Qp, SK, SQ, NC, NR, UG, SCAL);
  k_fuse<<<32 + 256, 512, 0, stream>>>(UG, SCAL, Kp, Vp, maskp, NR,
                                       NUMP, DENP, W3CNT, Zb);
  k_final<<<dim3(32, 64), 256, 0, stream>>>(Qp, NC, Zb, out);
}

// Round 16
// 79.902 us; speedup vs baseline: 1.1638x; 1.1638x over previous
//
#include <hip/hip_runtime.h>
#include <float.h>

#define BB 4
#define HH 8
#define BHN 32
#define NTOK 4096
#define DD 64
#define MM 64
#define PAD 68
#define GPART 16

typedef _Float16 f16;
typedef __attribute__((ext_vector_type(4))) _Float16 f16x4;
typedef __attribute__((ext_vector_type(8))) _Float16 f16x8;
typedef __attribute__((ext_vector_type(4))) float f32x4;

union V8U { f16x8 v; f16x4 q[2]; };

__device__ __forceinline__ void fsplit(float v, f16* h, f16* l) {
  f16 hh = (f16)v;
  *h = hh;
  *l = (f16)(v - (float)hh);
}

// plain f16 (2-chain)
__device__ __forceinline__ f32x4 mm2(f16x8 a0, f16x8 a1, f16x8 b0, f16x8 b1) {
  f32x4 c = {0.f, 0.f, 0.f, 0.f};
  c = __builtin_amdgcn_mfma_f32_16x16x32_f16(a0, b0, c, 0, 0, 0);
  c = __builtin_amdgcn_mfma_f32_16x16x32_f16(a1, b1, c, 0, 0, 0);
  return c;
}

// ---------------- 4x4-tile 64x64x64 matmul helper (fp32 scalar)
template<int LDA, int LDB>
__device__ __forceinline__ void mm_acc(float acc[4][4],
    const float (*A)[LDA], const float (*B)[LDB], int ti, int tj) {
  #pragma unroll
  for (int k4 = 0; k4 < 16; ++k4) {
    float a[4][4], b[4][4];
    #pragma unroll
    for (int x = 0; x < 4; ++x) {
      float4 t = *(const float4*)&A[ti*4+x][k4*4];
      a[x][0]=t.x; a[x][1]=t.y; a[x][2]=t.z; a[x][3]=t.w;
    }
    #pragma unroll
    for (int kk = 0; kk < 4; ++kk) {
      float4 t = *(const float4*)&B[k4*4+kk][tj*4];
      b[kk][0]=t.x; b[kk][1]=t.y; b[kk][2]=t.z; b[kk][3]=t.w;
    }
    #pragma unroll
    for (int kk = 0; kk < 4; ++kk)
      #pragma unroll
      for (int x = 0; x < 4; ++x)
        #pragma unroll
        for (int y = 0; y < 4; ++y)
          acc[x][y] = fmaf(a[x][kk], b[kk][y], acc[x][y]);
  }
}

// ---------------- row sums for selection (both K and Q), mask/token0 -> -FLT_MAX
__global__ __launch_bounds__(256) void k_somme(const float* __restrict__ Kg,
    const float* __restrict__ Qg, const int* __restrict__ mask,
    float* __restrict__ somK, float* __restrict__ somQ) {
  int tid = threadIdx.x;
  int lane = tid & 63;
  long grow = (long)blockIdx.x * 16 + (tid >> 6) * 4 + (lane >> 4);
  int which = grow >= (long)(BHN * NTOK);
  long row = which ? grow - (long)BHN * NTOK : grow;   // bh*N + n
  int n = (int)(row & (NTOK - 1));
  int bh = (int)(row >> 12);
  int b = bh >> 3;
  const float* src = which ? Qg : Kg;
  float4 v = *((const float4*)(src + row * DD) + (lane & 15));
  float s = v.x + v.y + v.z + v.w;
  s += __shfl_xor(s, 1); s += __shfl_xor(s, 2);
  s += __shfl_xor(s, 4); s += __shfl_xor(s, 8);
  if ((lane & 15) == 0) {
    float out = (n == 0 || mask[b * NTOK + n] != 0) ? -FLT_MAX : s;
    (which ? somQ : somK)[row] = out;
  }
}

// ---------------- per-(bh,which): radix top-63 select (wave-shfl scans) + gather
// Also zero-inits the k_fuse sync flags (block (0,0), thread 0).
__global__ __launch_bounds__(256) void k_select(const float* __restrict__ Kg,
    const float* __restrict__ Qg, const float* __restrict__ somK,
    const float* __restrict__ somQ, float* __restrict__ nc, float* __restrict__ nr,
    unsigned int* __restrict__ sync0) {
  int bh = blockIdx.x;
  int which = blockIdx.y;           // 0: K -> nc, 1: Q (scaled) -> nr
  if (which == 0 && bh == 0 && threadIdx.x == 0) {
    #pragma unroll
    for (int i = 0; i < 34; ++i) sync0[i] = 0u;    // SCAL, UFLAG, W3CNT[32]
  }
  __shared__ unsigned int keys[NTOK];       // 16KB
  __shared__ unsigned int wb[4][256];       // per-wave histograms, 4KB
  __shared__ int wsum[4];
  __shared__ int wsumB[4];
  __shared__ int sh_bin, sh_need;
  __shared__ int sel[MM];
  int tid = threadIdx.x, wave = tid >> 6, lane = tid & 63;
  const float* som = (which ? somQ : somK) + (long)bh * NTOK;
  for (int i = tid; i < NTOK; i += 256) {
    float f = som[i];
    unsigned int u = __float_as_uint(f);
    u = (u & 0x80000000u) ? ~u : (u | 0x80000000u);   // monotone map, ascending
    keys[i] = (i == 0) ? 0u : u;                      // token 0 out of competition
  }
  unsigned int pref = 0; int need = MM - 1;           // 63
  for (int pass = 0; pass < 4; ++pass) {
    int shift = 24 - pass * 8;
    unsigned int pm = (pass == 0) ? 0u : (0xFFFFFFFFu << (32 - 8 * pass));
    unsigned int* wbf = (unsigned int*)wb;
    wbf[tid] = 0; wbf[tid + 256] = 0; wbf[tid + 512] = 0; wbf[tid + 768] = 0;
    __syncthreads();
    for (int i = tid; i < NTOK; i += 256) {
      unsigned int k = keys[i];
      if ((k & pm) == pref) atomicAdd(&wb[wave][(k >> shift) & 255], 1u);
    }
    __syncthreads();
    int binr = 255 - tid;                             // reversed position -> suffix sum
    int cnt = (int)(wb[0][binr] + wb[1][binr] + wb[2][binr] + wb[3][binr]);
    int v = cnt;
    #pragma unroll
    for (int d = 1; d < 64; d <<= 1) {
      int t = __shfl_up(v, d);
      if (lane >= d) v += t;
    }
    if (lane == 63) wsum[wave] = v;
    __syncthreads();
    int off = 0;
    #pragma unroll
    for (int w = 0; w < 4; ++w) off += (w < wave) ? wsum[w] : 0;
    v += off;
    int above = v - cnt;
    if (v >= need && above < need) { sh_bin = binr; sh_need = need - above; }
    __syncthreads();
    pref |= ((unsigned int)sh_bin) << shift;
    need = sh_need;
  }
  unsigned int thr = pref;

  int base = tid * 16;
  int ctie = 0;
  #pragma unroll
  for (int j = 0; j < 16; ++j) ctie += (keys[base + j] == thr);
  int v2 = ctie;
  #pragma unroll
  for (int d = 1; d < 64; d <<= 1) {
    int t = __shfl_up(v2, d);
    if (lane >= d) v2 += t;
  }
  if (lane == 63) wsum[wave] = v2;
  __syncthreads();
  int offt = 0;
  #pragma unroll
  for (int w = 0; w < 4; ++w) offt += (w < wave) ? wsum[w] : 0;
  int tie_excl = v2 + offt - ctie;

  int tieoff = tie_excl, cnt2 = 0;
  #pragma unroll
  for (int j = 0; j < 16; ++j) {
    unsigned int k = keys[base + j];
    int f = (k > thr) ? 1 : 0;
    if (k == thr) { f = (tieoff < need) ? 1 : 0; ++tieoff; }
    if (base + j == 0) f = 1;
    cnt2 += f;
  }
  int v3 = cnt2;
  #pragma unroll
  for (int d = 1; d < 64; d <<= 1) {
    int t = __shfl_up(v3, d);
    if (lane >= d) v3 += t;
  }
  if (lane == 63) wsumB[wave] = v3;
  __syncthreads();
  int offc = 0;
  #pragma unroll
  for (int w = 0; w < 4; ++w) offc += (w < wave) ? wsumB[w] : 0;
  int o = v3 + offc - cnt2;
  tieoff = tie_excl;
  #pragma unroll
  for (int j = 0; j < 16; ++j) {
    unsigned int k = keys[base + j];
    int f = (k > thr) ? 1 : 0;
    if (k == thr) { f = (tieoff < need) ? 1 : 0; ++tieoff; }
    if (base + j == 0) f = 1;
    if (f) sel[o++] = base + j;
  }
  __syncthreads();

  const float* src = which ? Qg : Kg;
  float* dst = (which ? nr : nc) + (long)bh * MM * DD;
  float scale = which ? 0.125f : 1.0f;
  for (int e = tid; e < MM * 16; e += 256) {
    int i = e >> 4, d4 = e & 15;
    float4 v = *(const float4*)&src[((long)bh * NTOK + sel[i]) * DD + d4 * 4];
    v.x *= scale; v.y *= scale; v.z *= scale; v.w *= scale;
    *(float4*)&dst[i * DD + d4 * 4] = v;
  }
}

// =============== fused: u-compute + global-smax sync + Newton + Z (per bh block) =========
__device__ void newton_fused(char* smem, const float* __restrict__ nc,
    const float* __restrict__ nr, unsigned int* __restrict__ scal,
    unsigned int* __restrict__ uflag, const float* __restrict__ nump,
    const float* __restrict__ denp, unsigned int* __restrict__ w3cnt,
    float* __restrict__ Zg, int bh) {
  int tid = threadIdx.x;
  float* uL = (float*)(smem + 55296);            // 64x64 f32 (16KB)

  // ---- u-phase: u = row-softmax(nr @ nc^T) into uL; per-bh colsum max -> scal ----
  {
    float (*A)[PAD] = (float(*)[PAD])smem;                 // 17408
    float (*BT)[MM] = (float(*)[MM])(smem + 17408);        // 16384
    float (*cs)[MM] = (float(*)[MM])(smem + 33792);        // 1024
    if (tid < 256) {
      for (int e = tid; e < 1024; e += 256) {
        int m = e >> 4, d4 = e & 15;
        *(float4*)&A[m][d4*4] = *(const float4*)&nr[(long)bh*MM*DD + m*DD + d4*4];
        float4 c = *(const float4*)&nc[(long)bh*MM*DD + m*DD + d4*4];
        BT[d4*4+0][m] = c.x; BT[d4*4+1][m] = c.y; BT[d4*4+2][m] = c.z; BT[d4*4+3][m] = c.w;
      }
    }
    __syncthreads();
    if (tid < 256) {
      int ti = tid >> 4, tj = tid & 15;
      float acc[4][4] = {};
      mm_acc<PAD, MM>(acc, A, BT, ti, tj);
      float e_[4][4];
      #pragma unroll
      for (int x = 0; x < 4; ++x)
        #pragma unroll
        for (int y = 0; y < 4; ++y) e_[x][y] = expf(acc[x][y]);
      float rsx[4];
      #pragma unroll
      for (int x = 0; x < 4; ++x) {
        rsx[x] = e_[x][0] + e_[x][1] + e_[x][2] + e_[x][3];
        rsx[x] += __shfl_xor(rsx[x], 1); rsx[x] += __shfl_xor(rsx[x], 2);
        rsx[x] += __shfl_xor(rsx[x], 4); rsx[x] += __shfl_xor(rsx[x], 8);
      }
      float cp[4] = {0.f, 0.f, 0.f, 0.f};
      #pragma unroll
      for (int x = 0; x < 4; ++x) {
        float inv = 1.f / rsx[x];
        float v0 = e_[x][0]*inv, v1 = e_[x][1]*inv, v2 = e_[x][2]*inv, v3 = e_[x][3]*inv;
        cp[0] += v0; cp[1] += v1; cp[2] += v2; cp[3] += v3;
        float4 o; o.x = v0; o.y = v1; o.z = v2; o.w = v3;
        *(float4*)&uL[(ti*4+x)*MM + tj*4] = o;
      }
      #pragma unroll
      for (int y = 0; y < 4; ++y) {
        cp[y] += __shfl_xor(cp[y], 16);
        cp[y] += __shfl_xor(cp[y], 32);
      }
      if (((tid >> 4) & 3) == 0) {
        #pragma unroll
        for (int y = 0; y < 4; ++y) cs[tid >> 6][tj*4 + y] = cp[y];
      }
    }
    __syncthreads();
    if (tid < 64) {
      float tot = cs[0][tid] + cs[1][tid] + cs[2][tid] + cs[3][tid];
      for (int off = 32; off; off >>= 1) tot = fmaxf(tot, __shfl_xor(tot, off));
      if (tid == 0) atomicMax(scal, __float_as_uint(tot));   // colsums > 0
    }
    __syncthreads();
    if (tid == 0)
      __hip_atomic_fetch_add(uflag, 1u, __ATOMIC_RELEASE, __HIP_MEMORY_SCOPE_AGENT);
    // wait for all 32 blocks' maxes
    if (tid == 0) {
      while (__hip_atomic_load(uflag, __ATOMIC_ACQUIRE, __HIP_MEMORY_SCOPE_AGENT) < 32u)
        __builtin_amdgcn_s_sleep(1);
      unsigned int sv = __hip_atomic_load(scal, __ATOMIC_RELAXED, __HIP_MEMORY_SCOPE_AGENT);
      cs[0][0] = 1.0f / __uint_as_float(sv);
    }
    __syncthreads();
  }
  float c0 = ((float(*)[MM])(smem + 33792))[0][0];
  __syncthreads();

  // ---- Newton phase (8 waves; u from LDS) ----
  f16 (*VT_h)[72] = (f16(*)[72])(smem);
  f16 (*Vr_h)[72] = (f16(*)[72])(smem + 9216);
  f16 (*PT_h)[72] = (f16(*)[72])(smem + 18432);
  f16 (*PT_l)[72] = (f16(*)[72])(smem + 27648);
  f16 (*RT_h)[72] = (f16(*)[72])(smem + 36864);
  f16 (*RT_l)[72] = (f16(*)[72])(smem + 46080);
  float (*Vi)[PAD] = (float(*)[PAD])(smem + 36864);   // last-iter output (over RT)
  int wave = tid >> 6, lane = tid & 63;
  int wr = wave >> 1, wc = wave & 1;
  int lm = lane & 15, hi = lane >> 4;

  for (int e = tid; e < 4096; e += 512) {
    int i = e >> 6, j = e & 63;
    f16 h = (f16)(uL[e] * c0);
    VT_h[i][j] = h;                    // V0^T = c*K
    Vr_h[j][i] = h;                    // V0 = c*K^T
  }
  f16x8 kb_h[2], kb_l[2];
  {
    const float* p = uL + (wr*16 + lm) * 64;
    float kv[16];
    *(float4*)&kv[0]  = *(const float4*)(p + hi*8);
    *(float4*)&kv[4]  = *(const float4*)(p + hi*8 + 4);
    *(float4*)&kv[8]  = *(const float4*)(p + 32 + hi*8);
    *(float4*)&kv[12] = *(const float4*)(p + 36 + hi*8);
    #pragma unroll
    for (int j = 0; j < 8; ++j) {
      f16 h, l;
      fsplit(kv[j], &h, &l);     kb_h[0][j] = h; kb_l[0][j] = l;
      fsplit(kv[8+j], &h, &l);   kb_h[1][j] = h; kb_l[1][j] = l;
    }
  }
  __syncthreads();

  for (int it = 0; it < 6; ++it) {
    const bool last = (it == 5);

    // step 1: S^T slice = mfma(VT rows, K rows); split-K only when last
    f32x4 st[4];
    #pragma unroll
    for (int g = 0; g < 4; ++g) {
      f16x8 a0 = *(const f16x8*)&VT_h[g*16 + lm][hi*8];
      f16x8 a1 = *(const f16x8*)&VT_h[g*16 + lm][32 + hi*8];
      f32x4 c = mm2(a0, a1, kb_h[0], kb_h[1]);
      if (last) {
        c = __builtin_amdgcn_mfma_f32_16x16x32_f16(a0, kb_l[0], c, 0, 0, 0);
        c = __builtin_amdgcn_mfma_f32_16x16x32_f16(a1, kb_l[1], c, 0, 0, 0);
      }
      st[g] = c;
    }
    f16x8 sa[2];
    #pragma unroll
    for (int g = 0; g < 4; ++g)
      #pragma unroll
      for (int r = 0; r < 4; ++r)
        sa[g >> 1][(g & 1)*4 + r] = (f16)st[g][r];
    #pragma unroll
    for (int g = 0; g < 4; ++g) {
      if ((g >> 1) == wc) {
        #pragma unroll
        for (int r = 0; r < 4; ++r) {
          int i = g*16 + hi*4 + r, j = wr*16 + lm;
          float pv = (i == j ? 7.f : 0.f) - st[g][r];
          if (last) {
            f16 h, l; fsplit(pv, &h, &l);
            PT_h[i][j] = h; PT_l[i][j] = l;
          } else {
            PT_h[i][j] = (f16)pv;
          }
        }
      }
    }
    __syncthreads();

    // step 2: R = 15I - S@P -> RT
    #pragma unroll
    for (int cc2 = 0; cc2 < 2; ++cc2) {
      int cc = wc*2 + cc2;
      V8U bh0, bh1;
      bh0.q[0] = *(const f16x4*)&PT_h[cc*16 + lm][hi*4];
      bh0.q[1] = *(const f16x4*)&PT_h[cc*16 + lm][16 + hi*4];
      bh1.q[0] = *(const f16x4*)&PT_h[cc*16 + lm][32 + hi*4];
      bh1.q[1] = *(const f16x4*)&PT_h[cc*16 + lm][48 + hi*4];
      f32x4 a = mm2(sa[0], sa[1], bh0.v, bh1.v);
      if (last) {
        V8U bl0, bl1;
        bl0.q[0] = *(const f16x4*)&PT_l[cc*16 + lm][hi*4];
        bl0.q[1] = *(const f16x4*)&PT_l[cc*16 + lm][16 + hi*4];
        bl1.q[0] = *(const f16x4*)&PT_l[cc*16 + lm][32 + hi*4];
        bl1.q[1] = *(const f16x4*)&PT_l[cc*16 + lm][48 + hi*4];
        a = __builtin_amdgcn_mfma_f32_16x16x32_f16(sa[0], bl0.v, a, 0, 0, 0);
        a = __builtin_amdgcn_mfma_f32_16x16x32_f16(sa[1], bl1.v, a, 0, 0, 0);
      }
      f16x4 wh, wl;
      #pragma unroll
      for (int r = 0; r < 4; ++r) {
        int row = wr*16 + hi*4 + r, col = cc*16 + lm;
        float rv = (row == col ? 15.f : 0.f) - a[r];
        if (last) { f16 h, l; fsplit(rv, &h, &l); wh[r] = h; wl[r] = l; }
        else wh[r] = (f16)rv;
      }
      *(f16x4*)&RT_h[cc*16 + lm][wr*16 + hi*4] = wh;
      if (last) *(f16x4*)&RT_l[cc*16 + lm][wr*16 + hi*4] = wl;
    }
    __syncthreads();

    // step 3: W = 13I - S@R -> WT (into PT bufs)
    #pragma unroll
    for (int cc2 = 0; cc2 < 2; ++cc2) {
      int cc = wc*2 + cc2;
      V8U bh0, bh1;
      bh0.q[0] = *(const f16x4*)&RT_h[cc*16 + lm][hi*4];
      bh0.q[1] = *(const f16x4*)&RT_h[cc*16 + lm][16 + hi*4];
      bh1.q[0] = *(const f16x4*)&RT_h[cc*16 + lm][32 + hi*4];
      bh1.q[1] = *(const f16x4*)&RT_h[cc*16 + lm][48 + hi*4];
      f32x4 a = mm2(sa[0], sa[1], bh0.v, bh1.v);
      if (last) {
        V8U bl0, bl1;
        bl0.q[0] = *(const f16x4*)&RT_l[cc*16 + lm][hi*4];
        bl0.q[1] = *(const f16x4*)&RT_l[cc*16 + lm][16 + hi*4];
        bl1.q[0] = *(const f16x4*)&RT_l[cc*16 + lm][32 + hi*4];
        bl1.q[1] = *(const f16x4*)&RT_l[cc*16 + lm][48 + hi*4];
        a = __builtin_amdgcn_mfma_f32_16x16x32_f16(sa[0], bl0.v, a, 0, 0, 0);
        a = __builtin_amdgcn_mfma_f32_16x16x32_f16(sa[1], bl1.v, a, 0, 0, 0);
      }
      f16x4 wh, wl;
      #pragma unroll
      for (int r = 0; r < 4; ++r) {
        int row = wr*16 + hi*4 + r, col = cc*16 + lm;
        float wv = (row == col ? 13.f : 0.f) - a[r];
        if (last) { f16 h, l; fsplit(wv, &h, &l); wh[r] = h; wl[r] = l; }
        else wh[r] = (f16)wv;
      }
      *(f16x4*)&PT_h[cc*16 + lm][wr*16 + hi*4] = wh;
      if (last) *(f16x4*)&PT_l[cc*16 + lm][wr*16 + hi*4] = wl;
    }
    __syncthreads();

    // step 4: V' = 0.25 V@W
    f16x8 vh0 = *(const f16x8*)&Vr_h[wr*16 + lm][hi*8];
    f16x8 vh1 = *(const f16x8*)&Vr_h[wr*16 + lm][32 + hi*8];
    #pragma unroll
    for (int cc2 = 0; cc2 < 2; ++cc2) {
      int cc = wc*2 + cc2;
      f16x8 wh0 = *(const f16x8*)&PT_h[cc*16 + lm][hi*8];
      f16x8 wh1 = *(const f16x8*)&PT_h[cc*16 + lm][32 + hi*8];
      f32x4 a = mm2(vh0, vh1, wh0, wh1);
      if (last) {
        f16x8 wl0 = *(const f16x8*)&PT_l[cc*16 + lm][hi*8];
        f16x8 wl1 = *(const f16x8*)&PT_l[cc*16 + lm][32 + hi*8];
        a = __builtin_amdgcn_mfma_f32_16x16x32_f16(vh0, wl0, a, 0, 0, 0);
        a = __builtin_amdgcn_mfma_f32_16x16x32_f16(vh1, wl1, a, 0, 0, 0);
        #pragma unroll
        for (int r = 0; r < 4; ++r)
          Vi[wr*16 + hi*4 + r][cc*16 + lm] = 0.25f * a[r];
      } else {
        f16x4 th;
        #pragma unroll
        for (int r = 0; r < 4; ++r) {
          f16 h = (f16)(0.25f * a[r]);
          Vr_h[wr*16 + hi*4 + r][cc*16 + lm] = h;
          th[r] = h;
        }
        *(f16x4*)&VT_h[cc*16 + lm][wr*16 + hi*4] = th;
      }
    }
    __syncthreads();
  }

  // ---- Z phase: wait for this bh's w3 partials, then Z = Vinv @ (sum num / sum den) ----
  if (tid == 0) {
    while (__hip_atomic_load(&w3cnt[bh], __ATOMIC_ACQUIRE, __HIP_MEMORY_SCOPE_AGENT) < 8u)
      __builtin_amdgcn_s_sleep(1);
  }
  __syncthreads();
  float (*W)[PAD] = (float(*)[PAD])smem;            // over VT/Vr (free)
  float* dn = (float*)(smem + 54272);               // 256B after Vi
  if (tid < 64) {
    float s = 0.f;
    #pragma unroll
    for (int g = 0; g < GPART; ++g) s += denp[((long)bh * GPART + g) * MM + tid];
    dn[tid] = s;
  }
  __syncthreads();
  for (int e = tid; e < 1024; e += 512) {
    int m = e >> 4, d4 = e & 15;
    float4 s = {0.f, 0.f, 0.f, 0.f};
    #pragma unroll
    for (int g = 0; g < GPART; ++g) {
      float4 t = *(const float4*)&nump[((long)bh * GPART + g) * (MM*DD) + m*DD + d4*4];
      s.x += t.x; s.y += t.y; s.z += t.z; s.w += t.w;
    }
    float inv = 1.f / dn[m];
    s.x *= inv; s.y *= inv; s.z *= inv; s.w *= inv;
    *(float4*)&W[m][d4*4] = s;
  }
  __syncthreads();
  if (tid < 256) {
    int ti = tid >> 4, tj = tid & 15;
    float acc[4][4] = {};
    mm_acc<PAD, PAD>(acc, Vi, W, ti, tj);
    #pragma unroll
    for (int x = 0; x < 4; ++x) {
      float4 o; o.x = acc[x][0]; o.y = acc[x][1]; o.z = acc[x][2]; o.w = acc[x][3];
      *(float4*)&Zg[(long)bh*MM*DD + (ti*4+x)*DD + tj*4] = o;
    }
  }
}

// w3 as two independent 256-thread halves in a 512-thread block; releases w3cnt[bh]
__device__ void w3_dev(char* smem, const float* __restrict__ Kg,
    const float* __restrict__ Vg, const int* __restrict__ maskg,
    const float* __restrict__ nr, float* __restrict__ nump,
    float* __restrict__ denp, unsigned int* __restrict__ w3cnt, int idx) {
  int bh = idx >> 3, grp = idx & 7, b = bh >> 3;
  int tid = threadIdx.x;
  int half = tid >> 8, t = tid & 255;
  f16 (*Ks)[72] = (f16(*)[72])(smem + half * 18432);
  f16 (*Vs)[72] = (f16(*)[72])(smem + half * 18432 + 9216);
  float* kmul = (float*)(smem + 36864) + half * 64;
  int lane = tid & 63;
  int lm = lane & 15, hi = lane >> 4;
  int wv = t >> 6;
  int m0 = wv * 16;
  int gslot = grp * 2 + half;

  f16x8 nrf[2];
  {
    const float* p = nr + (long)bh*MM*DD + (long)(m0 + lm)*DD + hi*8;
    float4 q0 = *(const float4*)p;
    float4 q1 = *(const float4*)(p + 4);
    float4 q2 = *(const float4*)(p + 32);
    float4 q3 = *(const float4*)(p + 36);
    nrf[0][0]=(f16)q0.x; nrf[0][1]=(f16)q0.y; nrf[0][2]=(f16)q0.z; nrf[0][3]=(f16)q0.w;
    nrf[0][4]=(f16)q1.x; nrf[0][5]=(f16)q1.y; nrf[0][6]=(f16)q1.z; nrf[0][7]=(f16)q1.w;
    nrf[1][0]=(f16)q2.x; nrf[1][1]=(f16)q2.y; nrf[1][2]=(f16)q2.z; nrf[1][3]=(f16)q2.w;
    nrf[1][4]=(f16)q3.x; nrf[1][5]=(f16)q3.y; nrf[1][6]=(f16)q3.z; nrf[1][7]=(f16)q3.w;
  }

  f32x4 nacc[4];
  #pragma unroll
  for (int dt = 0; dt < 4; ++dt) nacc[dt] = (f32x4){0.f, 0.f, 0.f, 0.f};
  float dsum = 0.f;

  for (int sc = 0; sc < 4; ++sc) {
    int n0c = (gslot * 4 + sc) * 64;
    if (sc) __syncthreads();
    for (int s = t; s < 1024; s += 256) {
      int row = s >> 4, c4 = s & 15;
      float4 kv = *(const float4*)&Kg[((long)bh*NTOK + n0c + row)*DD + c4*4];
      float4 vv = *(const float4*)&Vg[((long)bh*NTOK + n0c + row)*DD + c4*4];
      f16x4 kk = {(f16)kv.x, (f16)kv.y, (f16)kv.z, (f16)kv.w};
      f16x4 vv4 = {(f16)vv.x, (f16)vv.y, (f16)vv.z, (f16)vv.w};
      *(f16x4*)&Ks[row][c4*4] = kk;
      *(f16x4*)&Vs[row][c4*4] = vv4;
    }
    if (t < 64) kmul[t] = maskg[b * NTOK + n0c + t] ? 1.f : 0.f;
    __syncthreads();

    f32x4 stv[4];
    #pragma unroll
    for (int g = 0; g < 4; ++g) {
      f16x8 a0 = *(const f16x8*)&Ks[g*16 + lm][hi*8];
      f16x8 a1 = *(const f16x8*)&Ks[g*16 + lm][32 + hi*8];
      stv[g] = mm2(a0, a1, nrf[0], nrf[1]);
    }
    f16x8 pa[2];
    #pragma unroll
    for (int g = 0; g < 4; ++g) {
      #pragma unroll
      for (int r = 0; r < 4; ++r) {
        float p = __expf(stv[g][r]) * kmul[g*16 + hi*4 + r];
        dsum += p;
        pa[g >> 1][(g & 1)*4 + r] = (f16)p;
      }
    }
    #pragma unroll
    for (int dt = 0; dt < 4; ++dt) {
      f16x8 vb0, vb1;
      #pragma unroll
      for (int j = 0; j < 8; ++j) {
        int nrow = hi*4 + (j & 3) + 16*(j >> 2);
        vb0[j] = Vs[nrow][dt*16 + lm];
        vb1[j] = Vs[32 + nrow][dt*16 + lm];
      }
      nacc[dt] = __builtin_amdgcn_mfma_f32_16x16x32_f16(pa[0], vb0, nacc[dt], 0, 0, 0);
      nacc[dt] = __builtin_amdgcn_mfma_f32_16x16x32_f16(pa[1], vb1, nacc[dt], 0, 0, 0);
    }
  }
  float* pnum = nump + ((long)bh * GPART + gslot) * (MM * DD);
  #pragma unroll
  for (int dt = 0; dt < 4; ++dt)
    #pragma unroll
    for (int r = 0; r < 4; ++r)
      pnum[(m0 + hi*4 + r)*DD + dt*16 + lm] = nacc[dt][r];
  float d2 = dsum + __shfl_xor(dsum, 16);
  d2 += __shfl_xor(d2, 32);
  if (lane < 16)
    denp[((long)bh * GPART + gslot) * MM + m0 + lane] = d2;
  __syncthreads();     // all global stores of the block drained (vmcnt(0) before barrier)
  if (tid == 0)
    __hip_atomic_fetch_add(&w3cnt[bh], 1u, __ATOMIC_RELEASE, __HIP_MEMORY_SCOPE_AGENT);
}

// merged launch: blocks [0,32) u+newton+z, blocks [32,288) w3. All 288 co-resident
// (LDS 71.7KB -> 2 blocks/CU) so spins are safe.
__global__ __launch_bounds__(512, 4) void k_fuse(
    const float* __restrict__ nc, const float* __restrict__ nr,
    unsigned int* __restrict__ scal, unsigned int* __restrict__ uflag,
    const float* __restrict__ Kg, const float* __restrict__ Vg,
    const int* __restrict__ maskg,
    float* __restrict__ nump, float* __restrict__ denp,
    unsigned int* __restrict__ w3cnt, float* __restrict__ Zg) {
  __shared__ __align__(16) char smem[71680];
  if (blockIdx.x < 32)
    newton_fused(smem, nc, nr, scal, uflag, nump, denp, w3cnt, Zg, blockIdx.x);
  else
    w3_dev(smem, Kg, Vg, maskg, nr, nump, denp, w3cnt, blockIdx.x - 32);
}

// ---------------- MFMA X = row-softmax(Qs @ nc^T) @ Z  (swapped S^T trick)
__global__ __launch_bounds__(256) void k_final(const float* __restrict__ Qg,
    const float* __restrict__ nc, const float* __restrict__ Zg, float* __restrict__ Xg) {
  int bh = blockIdx.x, chunk = blockIdx.y;
  int tid = threadIdx.x;
  int wave = tid >> 6, lane = tid & 63;
  int lm = lane & 15, hi = lane >> 4;
  int n0 = chunk * 64;
  __shared__ f16 Qs[64][72];
  __shared__ f16 Ncs[64][72];
  __shared__ f16 Zs[64][72];
  for (int s = tid; s < 1024; s += 256) {
    int row = s >> 4, c4 = s & 15;
    float4 q = *(const float4*)&Qg[((long)bh*NTOK + n0 + row)*DD + c4*4];
    f16x4 qq = {(f16)(q.x*0.125f), (f16)(q.y*0.125f), (f16)(q.z*0.125f), (f16)(q.w*0.125f)};
    *(f16x4*)&Qs[row][c4*4] = qq;
    float4 cv = *(const float4*)&nc[(long)bh*MM*DD + row*DD + c4*4];
    f16x4 cc = {(f16)cv.x, (f16)cv.y, (f16)cv.z, (f16)cv.w};
    *(f16x4*)&Ncs[row][c4*4] = cc;
    float4 zv = *(const float4*)&Zg[(long)bh*MM*DD + row*DD + c4*4];
    f16x4 zz = {(f16)zv.x, (f16)zv.y, (f16)zv.z, (f16)zv.w};
    *(f16x4*)&Zs[row][c4*4] = zz;
  }
  __syncthreads();

  f16x8 qb0 = *(const f16x8*)&Qs[wave*16 + lm][hi*8];
  f16x8 qb1 = *(const f16x8*)&Qs[wave*16 + lm][32 + hi*8];
  f32x4 stv[4];
  #pragma unroll
  for (int mt = 0; mt < 4; ++mt) {
    f16x8 a0 = *(const f16x8*)&Ncs[mt*16 + lm][hi*8];
    f16x8 a1 = *(const f16x8*)&Ncs[mt*16 + lm][32 + hi*8];
    stv[mt] = mm2(a0, a1, qb0, qb1);
  }
  f16x8 pa[2];
  float dsum = 0.f;
  #pragma unroll
  for (int mt = 0; mt < 4; ++mt) {
    #pragma unroll
    for (int r = 0; r < 4; ++r) {
      float p = __expf(stv[mt][r]);
      dsum += p;
      pa[mt >> 1][(mt & 1)*4 + r] = (f16)p;
    }
  }
  float dtot = dsum + __shfl_xor(dsum, 16);
  dtot += __shfl_xor(dtot, 32);
  f32x4 xacc[4];
  #pragma unroll
  for (int dt = 0; dt < 4; ++dt) {
    f16x8 zb0, zb1;
    #pragma unroll
    for (int j = 0; j < 8; ++j) {
      int mrow = hi*4 + (j & 3) + 16*(j >> 2);
      zb0[j] = Zs[mrow][dt*16 + lm];
      zb1[j] = Zs[32 + mrow][dt*16 + lm];
    }
    f32x4 c = {0.f, 0.f, 0.f, 0.f};
    c = __builtin_amdgcn_mfma_f32_16x16x32_f16(pa[0], zb0, c, 0, 0, 0);
    c = __builtin_amdgcn_mfma_f32_16x16x32_f16(pa[1], zb1, c, 0, 0, 0);
    xacc[dt] = c;
  }
  float rn[4];
  #pragma unroll
  for (int r = 0; r < 4; ++r) rn[r] = 1.f / __shfl(dtot, hi*4 + r);
  #pragma unroll
  for (int dt = 0; dt < 4; ++dt)
    #pragma unroll
    for (int r = 0; r < 4; ++r)
      Xg[((long)bh*NTOK + n0 + wave*16 + hi*4 + r)*DD + dt*16 + lm] = xacc[dt][r] * rn[r];
}

extern "C" void kernel_launch(void* const* d_in, const int* in_sizes, int n_in,
                              void* d_out, int out_size, void* d_ws, size_t ws_size,
                              hipStream_t stream) {
  (void)in_sizes; (void)n_in; (void)out_size; (void)ws_size;
  const float* Qp = (const float*)d_in[0];
  const float* Kp = (const float*)d_in[1];
  const float* Vp = (const float*)d_in[2];
  const int* maskp = (const int*)d_in[3];
  float* out = (float*)d_out;

  float* wsf = (float*)d_ws;
  float* NUMP = wsf;                                // 32*16*4096
  float* DENP = NUMP + (long)BHN * GPART * MM * DD; // 32*16*64
  unsigned int* SYNC = (unsigned int*)(DENP + BHN * GPART * MM); // [0]=SCAL [1]=UFLAG [2..34)=W3CNT
  float* NC = (float*)(SYNC + 64);
  float* NR = NC + BHN * MM * DD;
  float* Zb = NR + BHN * MM * DD;
  float* SK = Zb + BHN * MM * DD;
  float* SQ = SK + BHN * NTOK;

  unsigned int* SCAL = SYNC;
  unsigned int* UFLAG = SYNC + 1;
  unsigned int* W3CNT = SYNC + 2;

  k_somme<<<16384, 256, 0, stream>>>(Kp, Qp, maskp, SK, SQ);
  k_select<<<dim3(32, 2), 256, 0, stream>>>(Kp, Qp, SK, SQ, NC, NR, SYNC);
  k_fuse<<<32 + 256, 512, 0, stream>>>(NC, NR, SCAL, UFLAG, Kp, Vp, maskp,
                                       NUMP, DENP, W3CNT, Zb);
  k_final<<<dim3(32, 64), 256, 0, stream>>>(Qp, NC, Zb, out);
}